// Round 3
// baseline (704.607 us; speedup 1.0000x reference)
//
#include <hip/hip_runtime.h>
#include <hip/hip_cooperative_groups.h>
#include <cstdint>
#include <cstddef>

namespace cg = cooperative_groups;

// Asymm_3d_spconv: ResContextBlock + ReconBlock over submanifold sparse convs.
// Round 12: cooperative mega-kernel.
//  - job_dual2 fuses stage-2 convs (s=conv(A1,W12,P313), r=conv(A2,W3,P133))
//    AND the y=r+s add in one pass (bit-identical to R10's serialized path:
//    s goes through an in-register bf16 round-trip). add_y + R32 removed.
//  - Whole MFMA tier is ONE hipLaunchCooperativeKernel: prep -> sync ->
//    dual1 -> sync -> dual2 -> sync -> recon. grid=1024 @ lb(256,4) is
//    guaranteed co-resident (4 blocks/CU x 256 CU). Grid-stride over jobs.
//  - If the coop launch errors (capture-unsupported etc.), identical logic
//    runs as 4 plain launches. VALU fallback tier for tiny ws unchanged.

#define SLOPE 0.01f
#define BN_EPS 1e-5f

typedef __attribute__((ext_vector_type(8))) short bf16x8;
typedef __attribute__((ext_vector_type(4))) float f32x4;

__device__ __forceinline__ float bflo(uint32_t w) {
    union { uint32_t i; float f; } v; v.i = w << 16; return v.f;
}
__device__ __forceinline__ float bfhi(uint32_t w) {
    union { uint32_t i; float f; } v; v.i = w & 0xffff0000u; return v.f;
}
__device__ __forceinline__ float bf2f(uint16_t u) {
    union { uint32_t i; float f; } v; v.i = ((uint32_t)u) << 16; return v.f;
}
__device__ __forceinline__ uint16_t f2bf(float f) {  // RNE
    union { float f; uint32_t i; } v; v.f = f;
    uint32_t x = v.i;
    return (uint16_t)((x + 0x7fffu + ((x >> 16) & 1u)) >> 16);
}

struct Taps9 { int t[9]; };
struct WSrcs { const void* p[8]; };  // W1,W12,W2,W3,Wr1,Wr2,Wr3,bnp

// Wf: 5 stages x [t9][T2][co32][k32] shorts, 18432 each.
// CIN16 stages (0,2): k interleaved (c=k>>1, part=k&1); T0=[wh,wh], T1=[wl,0].
// CIN32 stages (1,3,4): k = channel; T0 = wh, T1 = wl. Stage 4 folds BN scale.
#define WFS     18432
#define WF_END  (5 * WFS)
#define BN_CNT  896
#define PREP_BLOCKS ((WF_END + BN_CNT + 255) / 256)

__device__ __forceinline__ int detect_f32_inline(const uint16_t* x16)
{
    int lane = threadIdx.x & 63;
    float a = bf2f(x16[4 * lane]);
    float b = bf2f(x16[4 * lane + 2]);
    int bad = (!(a > -16.f && a < 16.f)) || (!(b > -16.f && b < 16.f));
    return __ballot(bad) != 0ull;
}

__device__ __forceinline__ float readw(const void* p, int j, int f32)
{
    return f32 ? ((const float*)p)[j] : bf2f(((const uint16_t*)p)[j]);
}

// ---------------------------------------------------------------------------
// Element-wise prep bodies (shared by mega + standalone)
// ---------------------------------------------------------------------------
__device__ __forceinline__ void prep_weight_elem(int i, WSrcs srcs, int f32,
                                                 uint16_t* Wf, float* bnf)
{
    if (i < WF_END) {
        int s = i / WFS, r = i - s * WFS;
        int t = r >> 11, T = (r >> 10) & 1;
        int co = (r >> 5) & 31, k = r & 31;
        uint16_t outv;
        if (s == 0 || s == 2) {
            int c = k >> 1, p = k & 1;
            float w = readw(srcs.p[s == 0 ? 0 : 2], (t * 16 + c) * 32 + co, f32);
            uint16_t h = f2bf(w);
            outv = (T == 0) ? h : (p == 0 ? f2bf(w - bf2f(h)) : (uint16_t)0);
        } else {
            float w;
            if (s == 4) {
                int g = t / 3, kk = t - g * 3;
                const void* bnp = srcs.p[7];
                float ga = readw(bnp, (4 + g) * 128 + co, f32);
                float va = readw(bnp, (4 + g) * 128 + 96 + co, f32);
                float scl = ga * rsqrtf(va + BN_EPS);
                w = readw(srcs.p[4 + g], (kk * 32 + k) * 32 + co, f32) * scl;
            } else {
                w = readw(srcs.p[s == 1 ? 1 : 3], (t * 32 + k) * 32 + co, f32);
            }
            uint16_t h = f2bf(w);
            outv = (T == 0) ? h : f2bf(w - bf2f(h));
        }
        Wf[i] = outv;
    } else if (i < WF_END + BN_CNT) {
        bnf[i - WF_END] = readw(srcs.p[7], i - WF_END, f32);
    }
}

__device__ __forceinline__ void canon_elem(int i, const void* xsrc, int f32,
                                           uint32_t* xi)
{
    float v = f32 ? ((const float*)xsrc)[i] : bf2f(((const uint16_t*)xsrc)[i]);
    int row = i >> 4, c = i & 15;
    uint16_t h = f2bf(v);
    uint16_t l = f2bf(v - bf2f(h));
    xi[(size_t)row * 16 + c] = (uint32_t)h | ((uint32_t)l << 16);
}

#define MFMA_BF16(A, B, C) __builtin_amdgcn_mfma_f32_16x16x32_bf16(A, B, C, 0, 0, 0)

// ---------------------------------------------------------------------------
// job_dual1: stage-1 convs c1 (W1,P133) + c2 (W2,P313) fused over shared x.
// 15 unique taps; g0 = shared {12,13,14}, g1/g2 = P133-only, g3/g4 = P313-only.
// ---------------------------------------------------------------------------
__device__ __forceinline__ void job_dual1(int bx,
                                          const uint16_t* __restrict__ xi,
                                          const uint16_t* __restrict__ Wf0,
                                          const uint16_t* __restrict__ Wf2,
                                          const float*    __restrict__ bnf,
                                          const int*      __restrict__ nbr,
                                          uint16_t*       __restrict__ outA,
                                          uint16_t*       __restrict__ outB,
                                          int N)
{
    const int tid = threadIdx.x;
    const int n0  = bx * 128;
    const int lane = tid & 63;
    const int m = lane & 15, q = lane >> 4;
    const int vt0 = (tid >> 6) * 32;
    const bf16x8 Z8 = {0, 0, 0, 0, 0, 0, 0, 0};

    const int UT[15] = {12, 13, 14, 9, 10, 11, 15, 16, 17, 3, 4, 5, 21, 22, 23};
    const int SB[5]  = {3, 0, 6, 0, 6};   // weight slice base per group
    const int JS[5]  = {0, 1, 1, 2, 2};   // 0=both jobs, 1=A only, 2=B only

    int rows[15][2];
#pragma unroll
    for (int u = 0; u < 15; ++u)
#pragma unroll
        for (int vt = 0; vt < 2; ++vt) {
            int n = n0 + vt0 + vt * 16 + m;
            rows[u][vt] = (n < N) ? nbr[(size_t)UT[u] * N + n] : -1;
        }
    __builtin_amdgcn_sched_barrier(0);

    bool act[15][2];
#pragma unroll
    for (int u = 0; u < 15; ++u)
#pragma unroll
        for (int vt = 0; vt < 2; ++vt)
            act[u][vt] = __ballot(rows[u][vt] >= 0) != 0ull;

    f32x4 accA[2][2], accB[2][2];
#pragma unroll
    for (int vt = 0; vt < 2; ++vt)
#pragma unroll
        for (int ot = 0; ot < 2; ++ot) {
            accA[vt][ot] = {0.f, 0.f, 0.f, 0.f};
            accB[vt][ot] = {0.f, 0.f, 0.f, 0.f};
        }

#pragma unroll
    for (int g = 0; g < 5; ++g) {
        bf16x8 A[3][2];
#pragma unroll
        for (int i = 0; i < 3; ++i)
#pragma unroll
            for (int vt = 0; vt < 2; ++vt) {
                const int u = g * 3 + i;
                A[i][vt] = Z8;
                if (act[u][vt]) {
                    int row = rows[u][vt];
                    if (row >= 0)
                        A[i][vt] = *(const bf16x8*)(xi + (size_t)row * 32 + q * 8);
                }
            }
        __builtin_amdgcn_sched_barrier(0);

#pragma unroll
        for (int i = 0; i < 3; ++i) {
            const int u = g * 3 + i;
            if (!(act[u][0] || act[u][1])) continue;
            const int t = SB[g] + i;
            if (JS[g] != 2) {
                const uint16_t* wb = Wf0 + t * 2048 + m * 32 + q * 8;
                bf16x8 B00 = *(const bf16x8*)(wb);
                bf16x8 B10 = *(const bf16x8*)(wb + 1024);
                bf16x8 B01 = *(const bf16x8*)(wb + 512);
                bf16x8 B11 = *(const bf16x8*)(wb + 1536);
#pragma unroll
                for (int vt = 0; vt < 2; ++vt) {
                    if (!act[u][vt]) continue;
                    accA[vt][0] = MFMA_BF16(A[i][vt], B00, accA[vt][0]);
                    accA[vt][0] = MFMA_BF16(A[i][vt], B10, accA[vt][0]);
                    accA[vt][1] = MFMA_BF16(A[i][vt], B01, accA[vt][1]);
                    accA[vt][1] = MFMA_BF16(A[i][vt], B11, accA[vt][1]);
                }
            }
            if (JS[g] != 1) {
                const uint16_t* wb = Wf2 + t * 2048 + m * 32 + q * 8;
                bf16x8 B00 = *(const bf16x8*)(wb);
                bf16x8 B10 = *(const bf16x8*)(wb + 1024);
                bf16x8 B01 = *(const bf16x8*)(wb + 512);
                bf16x8 B11 = *(const bf16x8*)(wb + 1536);
#pragma unroll
                for (int vt = 0; vt < 2; ++vt) {
                    if (!act[u][vt]) continue;
                    accB[vt][0] = MFMA_BF16(A[i][vt], B00, accB[vt][0]);
                    accB[vt][0] = MFMA_BF16(A[i][vt], B10, accB[vt][0]);
                    accB[vt][1] = MFMA_BF16(A[i][vt], B01, accB[vt][1]);
                    accB[vt][1] = MFMA_BF16(A[i][vt], B11, accB[vt][1]);
                }
            }
        }
    }

#pragma unroll
    for (int jb = 0; jb < 2; ++jb) {
        const float* bn = bnf + (jb ? 2 * 128 : 0);
        uint16_t* out = jb ? outB : outA;
#pragma unroll
        for (int ot = 0; ot < 2; ++ot) {
            int ch = ot * 16 + m;
            float ga = bn[ch], be = bn[32 + ch];
            float mu = bn[64 + ch], va = bn[96 + ch];
            float s = ga * rsqrtf(va + BN_EPS);
            float b = be - mu * s;
#pragma unroll
            for (int vt = 0; vt < 2; ++vt)
#pragma unroll
                for (int r = 0; r < 4; ++r) {
                    int vox = n0 + vt0 + vt * 16 + q * 4 + r;
                    if (vox >= N) continue;
                    f32x4 av = jb ? accB[vt][ot] : accA[vt][ot];
                    float xv = av[r];
                    xv = (xv >= 0.f) ? xv : SLOPE * xv;
                    out[(size_t)vox * 32 + ch] = f2bf(xv * s + b);
                }
        }
    }
}

// ---------------------------------------------------------------------------
// job_dual2: stage-2 fused. Phase S: s = bn1(lrelu(conv(A1,W12,P313))) with
// bf16 round-trip kept in-register. Phase R: r = bn3(lrelu(conv(A2,W3,P133)));
// y = f2bf(r + bf2f(s)). Bit-identical to the R10 serialized c12->c3 path.
// ---------------------------------------------------------------------------
__device__ __forceinline__ void job_dual2(int bx,
                                          const uint16_t* __restrict__ A1f,
                                          const uint16_t* __restrict__ A2f,
                                          const uint16_t* __restrict__ Wf1,
                                          const uint16_t* __restrict__ Wf3,
                                          const float*    __restrict__ bnf,
                                          const int*      __restrict__ nbr,
                                          uint16_t*       __restrict__ y16,
                                          int N)
{
    const int tid = threadIdx.x;
    const int n0  = bx * 128;
    const int lane = tid & 63;
    const int m = lane & 15, q = lane >> 4;
    const int vt0 = (tid >> 6) * 32;
    const bf16x8 Z8 = {0, 0, 0, 0, 0, 0, 0, 0};

    uint16_t sv[2][2][4];

    // ---- phase S: taps P313 on A1 with Wf1, bn1 ----
    {
        const int TS[9] = {3, 4, 5, 12, 13, 14, 21, 22, 23};
        int rows[9][2];
#pragma unroll
        for (int t = 0; t < 9; ++t)
#pragma unroll
            for (int vt = 0; vt < 2; ++vt) {
                int n = n0 + vt0 + vt * 16 + m;
                rows[t][vt] = (n < N) ? nbr[(size_t)TS[t] * N + n] : -1;
            }
        __builtin_amdgcn_sched_barrier(0);

        bool act[9][2];
#pragma unroll
        for (int t = 0; t < 9; ++t)
#pragma unroll
            for (int vt = 0; vt < 2; ++vt)
                act[t][vt] = __ballot(rows[t][vt] >= 0) != 0ull;

        f32x4 acc[2][2];
#pragma unroll
        for (int vt = 0; vt < 2; ++vt)
#pragma unroll
            for (int ot = 0; ot < 2; ++ot) acc[vt][ot] = {0.f, 0.f, 0.f, 0.f};

#pragma unroll
        for (int g = 0; g < 3; ++g) {
            bf16x8 A[3][2];
#pragma unroll
            for (int i = 0; i < 3; ++i)
#pragma unroll
                for (int vt = 0; vt < 2; ++vt) {
                    const int t = g * 3 + i;
                    A[i][vt] = Z8;
                    if (act[t][vt]) {
                        int row = rows[t][vt];
                        if (row >= 0)
                            A[i][vt] = *(const bf16x8*)(A1f + (size_t)row * 32 + q * 8);
                    }
                }
            __builtin_amdgcn_sched_barrier(0);

#pragma unroll
            for (int i = 0; i < 3; ++i) {
                const int t = g * 3 + i;
                if (!(act[t][0] || act[t][1])) continue;
                const uint16_t* wb = Wf1 + t * 2048 + m * 32 + q * 8;
                bf16x8 B00 = *(const bf16x8*)(wb);
                bf16x8 B10 = *(const bf16x8*)(wb + 1024);
                bf16x8 B01 = *(const bf16x8*)(wb + 512);
                bf16x8 B11 = *(const bf16x8*)(wb + 1536);
#pragma unroll
                for (int vt = 0; vt < 2; ++vt) {
                    if (!act[t][vt]) continue;
                    acc[vt][0] = MFMA_BF16(A[i][vt], B00, acc[vt][0]);
                    acc[vt][0] = MFMA_BF16(A[i][vt], B10, acc[vt][0]);
                    acc[vt][1] = MFMA_BF16(A[i][vt], B01, acc[vt][1]);
                    acc[vt][1] = MFMA_BF16(A[i][vt], B11, acc[vt][1]);
                }
            }
        }

#pragma unroll
        for (int ot = 0; ot < 2; ++ot) {
            int ch = ot * 16 + m;
            const float* bn = bnf + 128;
            float ga = bn[ch], be = bn[32 + ch];
            float mu = bn[64 + ch], va = bn[96 + ch];
            float s = ga * rsqrtf(va + BN_EPS);
            float b = be - mu * s;
#pragma unroll
            for (int vt = 0; vt < 2; ++vt)
#pragma unroll
                for (int r = 0; r < 4; ++r) {
                    float xv = acc[vt][ot][r];
                    xv = (xv >= 0.f) ? xv : SLOPE * xv;
                    sv[vt][ot][r] = f2bf(xv * s + b);
                }
        }
    }

    // ---- phase R: taps P133 on A2 with Wf3, bn3; y = r + s ----
    {
        const int TR[9] = {9, 10, 11, 12, 13, 14, 15, 16, 17};
        int rows[9][2];
#pragma unroll
        for (int t = 0; t < 9; ++t)
#pragma unroll
            for (int vt = 0; vt < 2; ++vt) {
                int n = n0 + vt0 + vt * 16 + m;
                rows[t][vt] = (n < N) ? nbr[(size_t)TR[t] * N + n] : -1;
            }
        __builtin_amdgcn_sched_barrier(0);

        bool act[9][2];
#pragma unroll
        for (int t = 0; t < 9; ++t)
#pragma unroll
            for (int vt = 0; vt < 2; ++vt)
                act[t][vt] = __ballot(rows[t][vt] >= 0) != 0ull;

        f32x4 acc[2][2];
#pragma unroll
        for (int vt = 0; vt < 2; ++vt)
#pragma unroll
            for (int ot = 0; ot < 2; ++ot) acc[vt][ot] = {0.f, 0.f, 0.f, 0.f};

#pragma unroll
        for (int g = 0; g < 3; ++g) {
            bf16x8 A[3][2];
#pragma unroll
            for (int i = 0; i < 3; ++i)
#pragma unroll
                for (int vt = 0; vt < 2; ++vt) {
                    const int t = g * 3 + i;
                    A[i][vt] = Z8;
                    if (act[t][vt]) {
                        int row = rows[t][vt];
                        if (row >= 0)
                            A[i][vt] = *(const bf16x8*)(A2f + (size_t)row * 32 + q * 8);
                    }
                }
            __builtin_amdgcn_sched_barrier(0);

#pragma unroll
            for (int i = 0; i < 3; ++i) {
                const int t = g * 3 + i;
                if (!(act[t][0] || act[t][1])) continue;
                const uint16_t* wb = Wf3 + t * 2048 + m * 32 + q * 8;
                bf16x8 B00 = *(const bf16x8*)(wb);
                bf16x8 B10 = *(const bf16x8*)(wb + 1024);
                bf16x8 B01 = *(const bf16x8*)(wb + 512);
                bf16x8 B11 = *(const bf16x8*)(wb + 1536);
#pragma unroll
                for (int vt = 0; vt < 2; ++vt) {
                    if (!act[t][vt]) continue;
                    acc[vt][0] = MFMA_BF16(A[i][vt], B00, acc[vt][0]);
                    acc[vt][0] = MFMA_BF16(A[i][vt], B10, acc[vt][0]);
                    acc[vt][1] = MFMA_BF16(A[i][vt], B01, acc[vt][1]);
                    acc[vt][1] = MFMA_BF16(A[i][vt], B11, acc[vt][1]);
                }
            }
        }

#pragma unroll
        for (int ot = 0; ot < 2; ++ot) {
            int ch = ot * 16 + m;
            const float* bn = bnf + 3 * 128;
            float ga = bn[ch], be = bn[32 + ch];
            float mu = bn[64 + ch], va = bn[96 + ch];
            float s = ga * rsqrtf(va + BN_EPS);
            float b = be - mu * s;
#pragma unroll
            for (int vt = 0; vt < 2; ++vt)
#pragma unroll
                for (int r = 0; r < 4; ++r) {
                    int vox = n0 + vt0 + vt * 16 + q * 4 + r;
                    if (vox >= N) continue;
                    float xv = acc[vt][ot][r];
                    xv = (xv >= 0.f) ? xv : SLOPE * xv;
                    float o = xv * s + b + bf2f(sv[vt][ot][r]);
                    y16[(size_t)vox * 32 + ch] = f2bf(o);
                }
        }
    }
}

// ---------------------------------------------------------------------------
// job_recon: 7 unique taps on y. Per-axis-group accumulators with partial
// sigmoid epilogue. Center fragment loaded once. Ballot-skip.
// ---------------------------------------------------------------------------
__device__ __forceinline__ void job_recon(int bx,
                                          const uint16_t* __restrict__ y16,
                                          int out_f32,
                                          const int* __restrict__ nbr,
                                          const uint16_t* __restrict__ Wf4,
                                          const float* __restrict__ bnf,
                                          void* __restrict__ out_, int N)
{
    const int tid = threadIdx.x;
    const int n0  = bx * 128;
    const int lane = tid & 63;
    const int m = lane & 15, q = lane >> 4;
    const int vt0 = (tid >> 6) * 32;
    const bf16x8 Z8 = {0, 0, 0, 0, 0, 0, 0, 0};

    const int ut[7] = {4, 22, 10, 16, 12, 14, 13};
    int rows[7][2];
#pragma unroll
    for (int t = 0; t < 7; ++t)
#pragma unroll
        for (int vt = 0; vt < 2; ++vt) {
            int n = n0 + vt0 + vt * 16 + m;
            rows[t][vt] = (n < N) ? nbr[(size_t)ut[t] * N + n] : -1;
        }
    __builtin_amdgcn_sched_barrier(0);

    bool act[7][2];
#pragma unroll
    for (int t = 0; t < 7; ++t)
#pragma unroll
        for (int vt = 0; vt < 2; ++vt)
            act[t][vt] = __ballot(rows[t][vt] >= 0) != 0ull;

    bf16x8 A6[2];
#pragma unroll
    for (int vt = 0; vt < 2; ++vt) {
        int row = rows[6][vt];
        A6[vt] = Z8;
        if (row >= 0)
            A6[vt] = *(const bf16x8*)(y16 + (size_t)row * 32 + q * 8);
    }

    float gsum[2][2][4];
#pragma unroll
    for (int vt = 0; vt < 2; ++vt)
#pragma unroll
        for (int ot = 0; ot < 2; ++ot)
#pragma unroll
            for (int r = 0; r < 4; ++r) gsum[vt][ot][r] = 0.f;

#pragma unroll
    for (int g = 0; g < 3; ++g) {
        f32x4 acc[2][2];
#pragma unroll
        for (int vt = 0; vt < 2; ++vt)
#pragma unroll
            for (int ot = 0; ot < 2; ++ot) acc[vt][ot] = {0.f, 0.f, 0.f, 0.f};

        bf16x8 Ae[2][2];
#pragma unroll
        for (int s2 = 0; s2 < 2; ++s2)
#pragma unroll
            for (int vt = 0; vt < 2; ++vt) {
                const int slot = 2 * g + s2;
                Ae[s2][vt] = Z8;
                if (act[slot][vt]) {
                    int row = rows[slot][vt];
                    if (row >= 0)
                        Ae[s2][vt] = *(const bf16x8*)(y16 + (size_t)row * 32 + q * 8);
                }
            }
        __builtin_amdgcn_sched_barrier(0);

#pragma unroll
        for (int s2 = 0; s2 < 2; ++s2) {
            const int slot = 2 * g + s2;
            if (!(act[slot][0] || act[slot][1])) continue;
            const int t = g * 3 + s2 * 2;
            const uint16_t* wb = Wf4 + t * 2048 + m * 32 + q * 8;
            bf16x8 B00 = *(const bf16x8*)(wb);
            bf16x8 B10 = *(const bf16x8*)(wb + 1024);
            bf16x8 B01 = *(const bf16x8*)(wb + 512);
            bf16x8 B11 = *(const bf16x8*)(wb + 1536);
#pragma unroll
            for (int vt = 0; vt < 2; ++vt) {
                if (!act[slot][vt]) continue;
                acc[vt][0] = MFMA_BF16(Ae[s2][vt], B00, acc[vt][0]);
                acc[vt][0] = MFMA_BF16(Ae[s2][vt], B10, acc[vt][0]);
                acc[vt][1] = MFMA_BF16(Ae[s2][vt], B01, acc[vt][1]);
                acc[vt][1] = MFMA_BF16(Ae[s2][vt], B11, acc[vt][1]);
            }
        }
        {
            const uint16_t* wb = Wf4 + (g * 3 + 1) * 2048 + m * 32 + q * 8;
            bf16x8 B00 = *(const bf16x8*)(wb);
            bf16x8 B10 = *(const bf16x8*)(wb + 1024);
            bf16x8 B01 = *(const bf16x8*)(wb + 512);
            bf16x8 B11 = *(const bf16x8*)(wb + 1536);
#pragma unroll
            for (int vt = 0; vt < 2; ++vt) {
                acc[vt][0] = MFMA_BF16(A6[vt], B00, acc[vt][0]);
                acc[vt][0] = MFMA_BF16(A6[vt], B10, acc[vt][0]);
                acc[vt][1] = MFMA_BF16(A6[vt], B01, acc[vt][1]);
                acc[vt][1] = MFMA_BF16(A6[vt], B11, acc[vt][1]);
            }
        }

#pragma unroll
        for (int ot = 0; ot < 2; ++ot) {
            int ch = ot * 16 + m;
            const float* p = bnf + (size_t)(4 + g) * 128;
            float scl = p[ch] * rsqrtf(p[96 + ch] + BN_EPS);
            float sh = p[32 + ch] - p[64 + ch] * scl;
#pragma unroll
            for (int vt = 0; vt < 2; ++vt)
#pragma unroll
                for (int r = 0; r < 4; ++r)
                    gsum[vt][ot][r] +=
                        1.f / (1.f + __expf(-(acc[vt][ot][r] + sh)));
        }
    }

#pragma unroll
    for (int ot = 0; ot < 2; ++ot) {
        int ch = ot * 16 + m;
#pragma unroll
        for (int vt = 0; vt < 2; ++vt)
#pragma unroll
            for (int r = 0; r < 4; ++r) {
                int vox = n0 + vt0 + vt * 16 + q * 4 + r;
                if (vox >= N) continue;
                float o = gsum[vt][ot][r] * bf2f(y16[(size_t)vox * 32 + ch]);
                if (out_f32)
                    ((float*)out_)[(size_t)vox * 32 + ch] = o;
                else
                    ((uint16_t*)out_)[(size_t)vox * 32 + ch] = f2bf(o);
            }
    }
}

// ---------------------------------------------------------------------------
// Cooperative mega-kernel: prep -> dual1 -> dual2 -> recon with grid syncs.
// ---------------------------------------------------------------------------
struct MegaArgs {
    const void* x;
    const int*  nbr;
    WSrcs       srcs;
    uint16_t*   Wf;
    float*      bnf;
    uint16_t*   xi;
    uint16_t*   A1;
    uint16_t*   A2;
    uint16_t*   Y;
    void*       out;
    int N, gx, totalx;
};

__launch_bounds__(256, 4)
__global__ void mega_kernel(MegaArgs a)
{
    cg::grid_group grid = cg::this_grid();
    const int f32 = detect_f32_inline((const uint16_t*)a.x);
    const int tstride = gridDim.x * 256;

    for (int i = blockIdx.x * 256 + threadIdx.x; i < WF_END + BN_CNT; i += tstride)
        prep_weight_elem(i, a.srcs, f32, a.Wf, a.bnf);
    for (int i = blockIdx.x * 256 + threadIdx.x; i < a.totalx; i += tstride)
        canon_elem(i, a.x, f32, (uint32_t*)a.xi);
    grid.sync();

    for (int bx = blockIdx.x; bx < a.gx; bx += gridDim.x)
        job_dual1(bx, a.xi, a.Wf, a.Wf + 2 * WFS, a.bnf, a.nbr, a.A1, a.A2, a.N);
    grid.sync();

    for (int bx = blockIdx.x; bx < a.gx; bx += gridDim.x)
        job_dual2(bx, a.A1, a.A2, a.Wf + 1 * WFS, a.Wf + 3 * WFS, a.bnf, a.nbr,
                  a.Y, a.N);
    grid.sync();

    for (int bx = blockIdx.x; bx < a.gx; bx += gridDim.x)
        job_recon(bx, a.Y, f32, a.nbr, a.Wf + 4 * WFS, a.bnf, a.out, a.N);
}

// ---------------------------------------------------------------------------
// Standalone wrappers (fallback if cooperative launch is unavailable)
// ---------------------------------------------------------------------------
__global__ void prep_combo(const void* __restrict__ xsrc, WSrcs srcs,
                           uint16_t* __restrict__ Wf, float* __restrict__ bnf,
                           uint32_t* __restrict__ xi, int total)
{
    int f32 = detect_f32_inline((const uint16_t*)xsrc);
    int b = blockIdx.x;
    if (b < PREP_BLOCKS) {
        int i = b * 256 + threadIdx.x;
        if (i < WF_END + BN_CNT)
            prep_weight_elem(i, srcs, f32, Wf, bnf);
    } else {
        int start = (b - PREP_BLOCKS) * 256 + threadIdx.x;
        int stride = (gridDim.x - PREP_BLOCKS) * 256;
        for (int i = start; i < total; i += stride)
            canon_elem(i, xsrc, f32, xi);
    }
}

__launch_bounds__(256, 4)
__global__ void k_dual1(const uint16_t* __restrict__ xi,
                        const uint16_t* __restrict__ Wf,
                        const float* __restrict__ bnf,
                        const int* __restrict__ nbr,
                        uint16_t* __restrict__ outA,
                        uint16_t* __restrict__ outB, int N)
{
    job_dual1(blockIdx.x, xi, Wf, Wf + 2 * WFS, bnf, nbr, outA, outB, N);
}

__launch_bounds__(256, 4)
__global__ void k_dual2(const uint16_t* __restrict__ A1f,
                        const uint16_t* __restrict__ A2f,
                        const uint16_t* __restrict__ Wf,
                        const float* __restrict__ bnf,
                        const int* __restrict__ nbr,
                        uint16_t* __restrict__ y16, int N)
{
    job_dual2(blockIdx.x, A1f, A2f, Wf + 1 * WFS, Wf + 3 * WFS, bnf, nbr, y16, N);
}

__launch_bounds__(256, 4)
__global__ void k_recon(const uint16_t* __restrict__ y16,
                        const uint16_t* __restrict__ xprobe,
                        const int* __restrict__ nbr,
                        const uint16_t* __restrict__ Wf,
                        const float* __restrict__ bnf,
                        void* __restrict__ out_, int N)
{
    int out_f32 = detect_f32_inline(xprobe);
    job_recon(blockIdx.x, y16, out_f32, nbr, Wf + 4 * WFS, bnf, out_, N);
}

// ---------------------------------------------------------------------------
// Fallback VALU tier (round-4 proven) for tiny ws.
// ---------------------------------------------------------------------------
#define WC_W1   0
#define WC_W12  4608
#define WC_W2   13824
#define WC_W3   18432
#define WC_WR1  27648
#define WC_WR2  30720
#define WC_WR3  33792
#define WC_BNP  36864
#define WC_END  37760

__global__ void canon_weights_fb(WSrcs srcs, float* __restrict__ Wc,
                                 const uint16_t* __restrict__ xprobe)
{
    int f32 = detect_f32_inline(xprobe);
    const int offs[9] = {WC_W1, WC_W12, WC_W2, WC_W3, WC_WR1, WC_WR2,
                         WC_WR3, WC_BNP, WC_END};
    int i = blockIdx.x * 256 + threadIdx.x;
    if (i >= WC_END) return;
    int t = 0;
#pragma unroll
    for (int k = 1; k < 8; ++k) if (i >= offs[k]) t = k;
    Wc[i] = readw(srcs.p[t], i - offs[t], f32);
}

__global__ void canon_x_bf(const void* __restrict__ xsrc,
                           uint16_t* __restrict__ xc, int n)
{
    int f32 = detect_f32_inline((const uint16_t*)xsrc);
    for (int i = blockIdx.x * blockDim.x + threadIdx.x; i < n;
         i += gridDim.x * blockDim.x) {
        float v = f32 ? ((const float*)xsrc)[i]
                      : bf2f(((const uint16_t*)xsrc)[i]);
        xc[i] = f2bf(v);
    }
}

template<int CIN>
__launch_bounds__(256)
__global__ void conv_bn_lrelu_bf(const uint16_t* __restrict__ feat,
                                 const int* __restrict__ nbr,
                                 const float* __restrict__ Wg,
                                 const float* __restrict__ bnp,
                                 const uint16_t* __restrict__ addsrc,
                                 uint16_t* __restrict__ out,
                                 Taps9 taps, int N)
{
    __shared__ float Wl[9 * CIN * 32];
    __shared__ float fs[CIN][128];
    __shared__ int   sidx[128];
    __shared__ float bns[32], bnb[32];

    const int tid = threadIdx.x;
    const int n0  = blockIdx.x * 128;

    for (int i = tid; i < 9 * CIN * 32; i += 256) Wl[i] = Wg[i];
    if (tid < 32) {
        float g = bnp[tid], b = bnp[32 + tid];
        float mu = bnp[64 + tid], va = bnp[96 + tid];
        float s = g * rsqrtf(va + BN_EPS);
        bns[tid] = s; bnb[tid] = b - mu * s;
    }
    float acc[4][4];
#pragma unroll
    for (int v = 0; v < 4; ++v)
#pragma unroll
        for (int j = 0; j < 4; ++j) acc[v][j] = 0.f;

    const int vb = (tid >> 3) << 2, cg2 = (tid & 7) << 2;
    const int r = tid >> 1, h = tid & 1, j0 = h * (CIN / 2);

#pragma unroll 1
    for (int t = 0; t < 9; ++t) {
        __syncthreads();
        if (tid < 128) {
            int n = n0 + tid;
            sidx[tid] = (n < N) ? nbr[(size_t)taps.t[t] * N + n] : -1;
        }
        __syncthreads();
        int mm = sidx[r];
        if (mm >= 0) {
            const uint16_t* src = feat + (size_t)mm * CIN + j0;
#pragma unroll
            for (int qq = 0; qq < CIN / 2; qq += 8) {
                uint4 u = *reinterpret_cast<const uint4*>(src + qq);
                fs[j0 + qq + 0][r] = bflo(u.x); fs[j0 + qq + 1][r] = bfhi(u.x);
                fs[j0 + qq + 2][r] = bflo(u.y); fs[j0 + qq + 3][r] = bfhi(u.y);
                fs[j0 + qq + 4][r] = bflo(u.z); fs[j0 + qq + 5][r] = bfhi(u.z);
                fs[j0 + qq + 6][r] = bflo(u.w); fs[j0 + qq + 7][r] = bfhi(u.w);
            }
        } else {
#pragma unroll
            for (int qq = 0; qq < CIN / 2; ++qq) fs[j0 + qq][r] = 0.f;
        }
        __syncthreads();
        const float* wk = Wl + t * (CIN * 32) + cg2;
#pragma unroll
        for (int ci = 0; ci < CIN; ++ci) {
            float4 f = *reinterpret_cast<const float4*>(&fs[ci][vb]);
            float4 w = *reinterpret_cast<const float4*>(wk + ci * 32);
            acc[0][0] += f.x * w.x; acc[0][1] += f.x * w.y; acc[0][2] += f.x * w.z; acc[0][3] += f.x * w.w;
            acc[1][0] += f.y * w.x; acc[1][1] += f.y * w.y; acc[1][2] += f.y * w.z; acc[1][3] += f.y * w.w;
            acc[2][0] += f.z * w.x; acc[2][1] += f.z * w.y; acc[2][2] += f.z * w.z; acc[2][3] += f.z * w.w;
            acc[3][0] += f.w * w.x; acc[3][1] += f.w * w.y; acc[3][2] += f.w * w.z; acc[3][3] += f.w * w.w;
        }
    }
#pragma unroll
    for (int v = 0; v < 4; ++v) {
        int n = n0 + vb + v;
        if (n >= N) continue;
        ushort4 st;
        uint16_t* ov = (uint16_t*)&st;
#pragma unroll
        for (int j = 0; j < 4; ++j) {
            float x = acc[v][j];
            x = (x >= 0.f) ? x : SLOPE * x;
            float o = x * bns[cg2 + j] + bnb[cg2 + j];
            if (addsrc) o += bf2f(addsrc[(size_t)n * 32 + cg2 + j]);
            ov[j] = f2bf(o);
        }
        *reinterpret_cast<ushort4*>(out + (size_t)n * 32 + cg2) = st;
    }
}

__launch_bounds__(256, 4)
__global__ void recon_gate_bf(const uint16_t* __restrict__ y,
                              const int* __restrict__ nbr,
                              const float* __restrict__ Wc,
                              const uint16_t* __restrict__ xprobe,
                              void* __restrict__ out_, int N)
{
    __shared__ float Wl[3 * 32 * 32];
    __shared__ float fs[32][128];
    __shared__ int   sidx[128];
    __shared__ float scl[3][32], shf[3][32];

    const int tid = threadIdx.x;
    const int n0  = blockIdx.x * 128;
    const int out_f32 = detect_f32_inline(xprobe);

    if (tid < 96) {
        int g = tid >> 5, c = tid & 31;
        const float* p = Wc + WC_BNP + (size_t)(4 + g) * 128;
        float ga = p[c], be = p[32 + c], mu = p[64 + c], va = p[96 + c];
        float s = ga * rsqrtf(va + BN_EPS);
        scl[g][c] = s; shf[g][c] = be - mu * s;
    }
    const int vb = (tid >> 3) << 2, cg2 = (tid & 7) << 2;
    const int r = tid >> 1, h = tid & 1, j0 = h * 16;

    float gsum[4][4];
#pragma unroll
    for (int v = 0; v < 4; ++v)
#pragma unroll
        for (int j = 0; j < 4; ++j) gsum[v][j] = 0.f;

    const int taps[3][3] = {{4, 13, 22}, {10, 13, 16}, {12, 13, 14}};

#pragma unroll 1
    for (int g = 0; g < 3; ++g) {
        __syncthreads();
        {
            const float* src = Wc + WC_WR1 + g * 3072;
            for (int i = tid; i < 3072; i += 256)
                Wl[i] = src[i] * scl[g][i & 31];
        }
        float acc[4][4];
#pragma unroll
        for (int v = 0; v < 4; ++v)
#pragma unroll
            for (int j = 0; j < 4; ++j) acc[v][j] = 0.f;

#pragma unroll 1
        for (int k = 0; k < 3; ++k) {
            __syncthreads();
            if (tid < 128) {
                int n = n0 + tid;
                sidx[tid] = (n < N) ? nbr[(size_t)taps[g][k] * N + n] : -1;
            }
            __syncthreads();
            int mm = sidx[r];
            if (mm >= 0) {
                const uint16_t* src = y + (size_t)mm * 32 + j0;
#pragma unroll
                for (int qq = 0; qq < 16; qq += 8) {
                    uint4 u = *reinterpret_cast<const uint4*>(src + qq);
                    fs[j0 + qq + 0][r] = bflo(u.x); fs[j0 + qq + 1][r] = bfhi(u.x);
                    fs[j0 + qq + 2][r] = bflo(u.y); fs[j0 + qq + 3][r] = bfhi(u.y);
                    fs[j0 + qq + 4][r] = bflo(u.z); fs[j0 + qq + 5][r] = bfhi(u.z);
                    fs[j0 + qq + 6][r] = bflo(u.w); fs[j0 + qq + 7][r] = bfhi(u.w);
                }
            } else {
#pragma unroll
                for (int qq = 0; qq < 16; ++qq) fs[j0 + qq][r] = 0.f;
            }
            __syncthreads();
            const float* wk = Wl + k * (32 * 32) + cg2;
#pragma unroll
            for (int ci = 0; ci < 32; ++ci) {
                float4 f = *reinterpret_cast<const float4*>(&fs[ci][vb]);
                float4 w = *reinterpret_cast<const float4*>(wk + ci * 32);
                acc[0][0] += f.x * w.x; acc[0][1] += f.x * w.y; acc[0][2] += f.x * w.z; acc[0][3] += f.x * w.w;
                acc[1][0] += f.y * w.x; acc[1][1] += f.y * w.y; acc[1][2] += f.y * w.z; acc[1][3] += f.y * w.w;
                acc[2][0] += f.z * w.x; acc[2][1] += f.z * w.y; acc[2][2] += f.z * w.z; acc[2][3] += f.z * w.w;
                acc[3][0] += f.w * w.x; acc[3][1] += f.w * w.y; acc[3][2] += f.w * w.z; acc[3][3] += f.w * w.w;
            }
        }
#pragma unroll
        for (int v = 0; v < 4; ++v)
#pragma unroll
            for (int j = 0; j < 4; ++j) {
                float x = acc[v][j] + shf[g][cg2 + j];
                gsum[v][j] += 1.f / (1.f + __expf(-x));
            }
    }
#pragma unroll
    for (int v = 0; v < 4; ++v) {
        int n = n0 + vb + v;
        if (n >= N) continue;
#pragma unroll
        for (int j = 0; j < 4; ++j) {
            float yv = bf2f(y[(size_t)n * 32 + cg2 + j]);
            float o = gsum[v][j] * yv;
            if (out_f32) ((float*)out_)[(size_t)n * 32 + cg2 + j] = o;
            else ((uint16_t*)out_)[(size_t)n * 32 + cg2 + j] = f2bf(o);
        }
    }
}

// ---------------------------------------------------------------------------
extern "C" void kernel_launch(void* const* d_in, const int* in_sizes, int n_in,
                              void* d_out, int out_size, void* d_ws, size_t ws_size,
                              hipStream_t stream)
{
    (void)n_in; (void)out_size;
    const void* x   = d_in[0];
    const int*  nbr = (const int*)d_in[1];
    const int N = in_sizes[0] / 16;
    const uint16_t* xprobe = (const uint16_t*)x;

    dim3 block(256);
    const int gx = (N + 127) / 128;
    WSrcs ws8 = {{ d_in[2], d_in[3], d_in[4], d_in[5],
                   d_in[6], d_in[7], d_in[8], d_in[9] }};

    // ws layout (MFMA tier): bnf [0,4096) | Wf [4096,+184320) | xi | A1 | A2 | Y
    float*    bnf = (float*)d_ws;
    uint16_t* Wf  = (uint16_t*)((char*)d_ws + 4096);
    const size_t base2 = 4096u + (size_t)WF_END * 2;   // 188416
    uint16_t* xi  = (uint16_t*)((char*)d_ws + base2);  // [N][32] interleaved
    uint16_t* A1  = xi + (size_t)N * 32;               // [N][32] bf16-hi
    uint16_t* A2  = A1 + (size_t)N * 32;
    uint16_t* Y   = A2 + (size_t)N * 32;
    const size_t need = base2 + 4u * (size_t)N * 64;

    if (ws_size >= need) {
        MegaArgs ma;
        ma.x = x; ma.nbr = nbr; ma.srcs = ws8;
        ma.Wf = Wf; ma.bnf = bnf; ma.xi = xi;
        ma.A1 = A1; ma.A2 = A2; ma.Y = Y; ma.out = d_out;
        ma.N = N; ma.gx = gx; ma.totalx = N * 16;
        void* kp[] = { (void*)&ma };
        hipError_t e = hipLaunchCooperativeKernel(
            (const void*)mega_kernel, dim3(1024), dim3(256), kp, 0, stream);
        if (e != hipSuccess) {
            // plain-launch fallback (same device logic, 4 launches)
            prep_combo<<<PREP_BLOCKS + 1024, block, 0, stream>>>(
                x, ws8, Wf, bnf, (uint32_t*)xi, N * 16);
            k_dual1<<<gx, block, 0, stream>>>(xi, Wf, bnf, nbr, A1, A2, N);
            k_dual2<<<gx, block, 0, stream>>>(A1, A2, Wf, bnf, nbr, Y, N);
            k_recon<<<gx, block, 0, stream>>>(Y, xprobe, nbr, Wf, bnf, d_out, N);
        }
    } else {
        // VALU fallback (all-bf16)
        Taps9 p133 = {{9, 10, 11, 12, 13, 14, 15, 16, 17}};
        Taps9 p313 = {{3, 4, 5, 12, 13, 14, 21, 22, 23}};
        float*    Wc = (float*)d_ws;
        uint16_t* xc = (uint16_t*)((char*)d_ws + (size_t)WC_END * 4 + 256);
        uint16_t* A  = (uint16_t*)d_out;
        uint16_t* B  = xc + (size_t)N * 16;
        const float* bn0 = Wc + WC_BNP + 0 * 128;
        const float* bn1 = Wc + WC_BNP + 1 * 128;
        const float* bn2 = Wc + WC_BNP + 2 * 128;
        const float* bn3 = Wc + WC_BNP + 3 * 128;
        canon_weights_fb<<<(WC_END + 255) / 256, block, 0, stream>>>(ws8, Wc, xprobe);
        canon_x_bf<<<1024, block, 0, stream>>>(x, xc, N * 16);
        conv_bn_lrelu_bf<16><<<gx, block, 0, stream>>>(xc, nbr, Wc + WC_W1,  bn0, nullptr, A, p133, N);
        conv_bn_lrelu_bf<32><<<gx, block, 0, stream>>>(A,  nbr, Wc + WC_W12, bn1, nullptr, B, p313, N);
        conv_bn_lrelu_bf<16><<<gx, block, 0, stream>>>(xc, nbr, Wc + WC_W2,  bn2, nullptr, A, p313, N);
        conv_bn_lrelu_bf<32><<<gx, block, 0, stream>>>(A,  nbr, Wc + WC_W3,  bn3, B,       B, p133, N);
        recon_gate_bf<<<gx, block, 0, stream>>>(B, nbr, Wc, xprobe, d_out, N);
    }
}

// Round 5
// 162.991 us; speedup vs baseline: 4.3230x; 4.3230x over previous
//
#include <hip/hip_runtime.h>
#include <cstdint>
#include <cstddef>

// Asymm_3d_spconv: ResContextBlock + ReconBlock over submanifold sparse convs.
// Round 14 == Round 13 resubmitted (R13 bench failed on container acquisition,
// not kernel error). Plan of record:
//   1) prep+canon merged (prep_combo).
//   2) stage 1 = R10's proven conv_mfma6 with gy=2 (c1,c2 one launch).
//   3) stage 2 = k_dual2 (hardware-validated in R12): s=conv(A1,W12,P313)
//      and r=conv(A2,W3,P133) in one block, y=f2bf(r+bf2f(s)) fused;
//      phases sequential so VGPR stays ~110.
//   4) recon.
// 4 launches total (R10: 6 @ 170.7us). VALU fallback tier unchanged.

#define SLOPE 0.01f
#define BN_EPS 1e-5f

typedef __attribute__((ext_vector_type(8))) short bf16x8;
typedef __attribute__((ext_vector_type(4))) float f32x4;

__device__ __forceinline__ float bflo(uint32_t w) {
    union { uint32_t i; float f; } v; v.i = w << 16; return v.f;
}
__device__ __forceinline__ float bfhi(uint32_t w) {
    union { uint32_t i; float f; } v; v.i = w & 0xffff0000u; return v.f;
}
__device__ __forceinline__ float bf2f(uint16_t u) {
    union { uint32_t i; float f; } v; v.i = ((uint32_t)u) << 16; return v.f;
}
__device__ __forceinline__ uint16_t f2bf(float f) {  // RNE
    union { float f; uint32_t i; } v; v.f = f;
    uint32_t x = v.i;
    return (uint16_t)((x + 0x7fffu + ((x >> 16) & 1u)) >> 16);
}

struct Taps9 { int t[9]; };
struct WSrcs { const void* p[8]; };  // W1,W12,W2,W3,Wr1,Wr2,Wr3,bnp

// Wf: 5 stages x [t9][T2][co32][k32] shorts, 18432 each.
// CIN16 stages (0,2): k interleaved (c=k>>1, part=k&1); T0=[wh,wh], T1=[wl,0].
// CIN32 stages (1,3,4): k = channel; T0 = wh, T1 = wl. Stage 4 folds BN scale.
#define WFS     18432
#define WF_END  (5 * WFS)
#define BN_CNT  896
#define PREP_BLOCKS ((WF_END + BN_CNT + 255) / 256)

__device__ __forceinline__ int detect_f32_inline(const uint16_t* x16)
{
    int lane = threadIdx.x & 63;
    float a = bf2f(x16[4 * lane]);
    float b = bf2f(x16[4 * lane + 2]);
    int bad = (!(a > -16.f && a < 16.f)) || (!(b > -16.f && b < 16.f));
    return __ballot(bad) != 0ull;
}

__device__ __forceinline__ float readw(const void* p, int j, int f32)
{
    return f32 ? ((const float*)p)[j] : bf2f(((const uint16_t*)p)[j]);
}

// ---------------------------------------------------------------------------
// Element-wise prep bodies
// ---------------------------------------------------------------------------
__device__ __forceinline__ void prep_weight_elem(int i, WSrcs srcs, int f32,
                                                 uint16_t* Wf, float* bnf)
{
    if (i < WF_END) {
        int s = i / WFS, r = i - s * WFS;
        int t = r >> 11, T = (r >> 10) & 1;
        int co = (r >> 5) & 31, k = r & 31;
        uint16_t outv;
        if (s == 0 || s == 2) {
            int c = k >> 1, p = k & 1;
            float w = readw(srcs.p[s == 0 ? 0 : 2], (t * 16 + c) * 32 + co, f32);
            uint16_t h = f2bf(w);
            outv = (T == 0) ? h : (p == 0 ? f2bf(w - bf2f(h)) : (uint16_t)0);
        } else {
            float w;
            if (s == 4) {
                int g = t / 3, kk = t - g * 3;
                const void* bnp = srcs.p[7];
                float ga = readw(bnp, (4 + g) * 128 + co, f32);
                float va = readw(bnp, (4 + g) * 128 + 96 + co, f32);
                float scl = ga * rsqrtf(va + BN_EPS);
                w = readw(srcs.p[4 + g], (kk * 32 + k) * 32 + co, f32) * scl;
            } else {
                w = readw(srcs.p[s == 1 ? 1 : 3], (t * 32 + k) * 32 + co, f32);
            }
            uint16_t h = f2bf(w);
            outv = (T == 0) ? h : f2bf(w - bf2f(h));
        }
        Wf[i] = outv;
    } else if (i < WF_END + BN_CNT) {
        bnf[i - WF_END] = readw(srcs.p[7], i - WF_END, f32);
    }
}

__device__ __forceinline__ void canon_elem(int i, const void* xsrc, int f32,
                                           uint32_t* xi)
{
    float v = f32 ? ((const float*)xsrc)[i] : bf2f(((const uint16_t*)xsrc)[i]);
    int row = i >> 4, c = i & 15;
    uint16_t h = f2bf(v);
    uint16_t l = f2bf(v - bf2f(h));
    xi[(size_t)row * 16 + c] = (uint32_t)h | ((uint32_t)l << 16);
}

__global__ void prep_combo(const void* __restrict__ xsrc, WSrcs srcs,
                           uint16_t* __restrict__ Wf, float* __restrict__ bnf,
                           uint32_t* __restrict__ xi, int total)
{
    int f32 = detect_f32_inline((const uint16_t*)xsrc);
    int b = blockIdx.x;
    if (b < PREP_BLOCKS) {
        int i = b * 256 + threadIdx.x;
        if (i < WF_END + BN_CNT)
            prep_weight_elem(i, srcs, f32, Wf, bnf);
    } else {
        int start = (b - PREP_BLOCKS) * 256 + threadIdx.x;
        int stride = (gridDim.x - PREP_BLOCKS) * 256;
        for (int i = start; i < total; i += stride)
            canon_elem(i, xsrc, f32, xi);
    }
}

#define MFMA_BF16(A, B, C) __builtin_amdgcn_mfma_f32_16x16x32_bf16(A, B, C, 0, 0, 0)

// ---------------------------------------------------------------------------
// conv_mfma6 (R10-proven): 64B feat rows. 256 thr = 4 waves, 128 vox/block;
// wave: 32 vox x 32 co. Ballot-mask skip; taps in 3 groups of 3 with batched
// A loads fenced from MFMA.
// ---------------------------------------------------------------------------
struct ConvJob {
    const uint16_t* feat;    // [N][32] shorts (64B rows)
    const uint16_t* Wf;      // stage base [9][2][32][32]
    const float*    bn;      // 128 floats gamma/beta/mean/var
    const uint16_t* addsrc;  // nullable [N][32] bf16-hi
    uint16_t*       out;     // [N][32] bf16-hi
    Taps9 taps;
};

__launch_bounds__(256, 4)
__global__ void conv_mfma6(ConvJob j0, ConvJob j1,
                           const int* __restrict__ nbr, int N)
{
    const ConvJob J = (blockIdx.y == 1) ? j1 : j0;
    const int tid = threadIdx.x;
    const int n0  = blockIdx.x * 128;
    const int lane = tid & 63;
    const int m = lane & 15, q = lane >> 4;
    const int vt0 = (tid >> 6) * 32;
    const bf16x8 Z8 = {0, 0, 0, 0, 0, 0, 0, 0};

    int rows[9][2];
#pragma unroll
    for (int t = 0; t < 9; ++t)
#pragma unroll
        for (int vt = 0; vt < 2; ++vt) {
            int n = n0 + vt0 + vt * 16 + m;
            rows[t][vt] = (n < N) ? nbr[(size_t)J.taps.t[t] * N + n] : -1;
        }
    __builtin_amdgcn_sched_barrier(0);

    bool act[9][2];
#pragma unroll
    for (int t = 0; t < 9; ++t)
#pragma unroll
        for (int vt = 0; vt < 2; ++vt)
            act[t][vt] = __ballot(rows[t][vt] >= 0) != 0ull;

    f32x4 acc[2][2];
#pragma unroll
    for (int vt = 0; vt < 2; ++vt)
#pragma unroll
        for (int ot = 0; ot < 2; ++ot) acc[vt][ot] = {0.f, 0.f, 0.f, 0.f};

#pragma unroll
    for (int g = 0; g < 3; ++g) {
        bf16x8 A[3][2];
#pragma unroll
        for (int i = 0; i < 3; ++i)
#pragma unroll
            for (int vt = 0; vt < 2; ++vt) {
                const int t = g * 3 + i;
                A[i][vt] = Z8;
                if (act[t][vt]) {
                    int row = rows[t][vt];
                    if (row >= 0)
                        A[i][vt] = *(const bf16x8*)(J.feat + (size_t)row * 32 + q * 8);
                }
            }
        __builtin_amdgcn_sched_barrier(0);

#pragma unroll
        for (int i = 0; i < 3; ++i) {
            const int t = g * 3 + i;
            if (!(act[t][0] || act[t][1])) continue;
            const uint16_t* wb = J.Wf + t * 2048 + m * 32 + q * 8;
            bf16x8 B00 = *(const bf16x8*)(wb);               // T0 ot0
            bf16x8 B10 = *(const bf16x8*)(wb + 1024);        // T1 ot0
            bf16x8 B01 = *(const bf16x8*)(wb + 512);         // T0 ot1
            bf16x8 B11 = *(const bf16x8*)(wb + 1536);        // T1 ot1
#pragma unroll
            for (int vt = 0; vt < 2; ++vt) {
                if (!act[t][vt]) continue;
                acc[vt][0] = MFMA_BF16(A[i][vt], B00, acc[vt][0]);
                acc[vt][0] = MFMA_BF16(A[i][vt], B10, acc[vt][0]);
                acc[vt][1] = MFMA_BF16(A[i][vt], B01, acc[vt][1]);
                acc[vt][1] = MFMA_BF16(A[i][vt], B11, acc[vt][1]);
            }
        }
    }

    // epilogue: C layout col=lane&15 (out-ch), row=quad*4+reg (voxel)
#pragma unroll
    for (int ot = 0; ot < 2; ++ot) {
        int ch = ot * 16 + m;
        float ga = J.bn[ch], be = J.bn[32 + ch];
        float mu = J.bn[64 + ch], va = J.bn[96 + ch];
        float s = ga * rsqrtf(va + BN_EPS);
        float b = be - mu * s;
#pragma unroll
        for (int vt = 0; vt < 2; ++vt)
#pragma unroll
            for (int r = 0; r < 4; ++r) {
                int vox = n0 + vt0 + vt * 16 + q * 4 + r;
                if (vox >= N) continue;
                float xv = acc[vt][ot][r];
                xv = (xv >= 0.f) ? xv : SLOPE * xv;
                float o = xv * s + b;
                if (J.addsrc) o += bf2f(J.addsrc[(size_t)vox * 32 + ch]);
                J.out[(size_t)vox * 32 + ch] = f2bf(o);
            }
    }
}

// ---------------------------------------------------------------------------
// k_dual2 (R12-hardware-validated): stage-2 fused. Phase S computes
// s = bn1(lrelu(conv(A1,W12,P313))) with the bf16 round-trip kept in-register;
// Phase R computes r = bn3(lrelu(conv(A2,W3,P133))); y = f2bf(r + bf2f(s)).
// Bit-identical to the R10 serialized c12->c3 path.
// ---------------------------------------------------------------------------
__launch_bounds__(256, 4)
__global__ void k_dual2(const uint16_t* __restrict__ A1f,
                        const uint16_t* __restrict__ A2f,
                        const uint16_t* __restrict__ Wf1,
                        const uint16_t* __restrict__ Wf3,
                        const float*    __restrict__ bnf,
                        const int*      __restrict__ nbr,
                        uint16_t*       __restrict__ y16, int N)
{
    const int tid = threadIdx.x;
    const int n0  = blockIdx.x * 128;
    const int lane = tid & 63;
    const int m = lane & 15, q = lane >> 4;
    const int vt0 = (tid >> 6) * 32;
    const bf16x8 Z8 = {0, 0, 0, 0, 0, 0, 0, 0};

    uint16_t sv[2][2][4];

    // ---- phase S: taps P313 on A1 with Wf1, bn1 ----
    {
        const int TS[9] = {3, 4, 5, 12, 13, 14, 21, 22, 23};
        int rows[9][2];
#pragma unroll
        for (int t = 0; t < 9; ++t)
#pragma unroll
            for (int vt = 0; vt < 2; ++vt) {
                int n = n0 + vt0 + vt * 16 + m;
                rows[t][vt] = (n < N) ? nbr[(size_t)TS[t] * N + n] : -1;
            }
        __builtin_amdgcn_sched_barrier(0);

        bool act[9][2];
#pragma unroll
        for (int t = 0; t < 9; ++t)
#pragma unroll
            for (int vt = 0; vt < 2; ++vt)
                act[t][vt] = __ballot(rows[t][vt] >= 0) != 0ull;

        f32x4 acc[2][2];
#pragma unroll
        for (int vt = 0; vt < 2; ++vt)
#pragma unroll
            for (int ot = 0; ot < 2; ++ot) acc[vt][ot] = {0.f, 0.f, 0.f, 0.f};

#pragma unroll
        for (int g = 0; g < 3; ++g) {
            bf16x8 A[3][2];
#pragma unroll
            for (int i = 0; i < 3; ++i)
#pragma unroll
                for (int vt = 0; vt < 2; ++vt) {
                    const int t = g * 3 + i;
                    A[i][vt] = Z8;
                    if (act[t][vt]) {
                        int row = rows[t][vt];
                        if (row >= 0)
                            A[i][vt] = *(const bf16x8*)(A1f + (size_t)row * 32 + q * 8);
                    }
                }
            __builtin_amdgcn_sched_barrier(0);

#pragma unroll
            for (int i = 0; i < 3; ++i) {
                const int t = g * 3 + i;
                if (!(act[t][0] || act[t][1])) continue;
                const uint16_t* wb = Wf1 + t * 2048 + m * 32 + q * 8;
                bf16x8 B00 = *(const bf16x8*)(wb);
                bf16x8 B10 = *(const bf16x8*)(wb + 1024);
                bf16x8 B01 = *(const bf16x8*)(wb + 512);
                bf16x8 B11 = *(const bf16x8*)(wb + 1536);
#pragma unroll
                for (int vt = 0; vt < 2; ++vt) {
                    if (!act[t][vt]) continue;
                    acc[vt][0] = MFMA_BF16(A[i][vt], B00, acc[vt][0]);
                    acc[vt][0] = MFMA_BF16(A[i][vt], B10, acc[vt][0]);
                    acc[vt][1] = MFMA_BF16(A[i][vt], B01, acc[vt][1]);
                    acc[vt][1] = MFMA_BF16(A[i][vt], B11, acc[vt][1]);
                }
            }
        }

#pragma unroll
        for (int ot = 0; ot < 2; ++ot) {
            int ch = ot * 16 + m;
            const float* bn = bnf + 128;
            float ga = bn[ch], be = bn[32 + ch];
            float mu = bn[64 + ch], va = bn[96 + ch];
            float s = ga * rsqrtf(va + BN_EPS);
            float b = be - mu * s;
#pragma unroll
            for (int vt = 0; vt < 2; ++vt)
#pragma unroll
                for (int r = 0; r < 4; ++r) {
                    float xv = acc[vt][ot][r];
                    xv = (xv >= 0.f) ? xv : SLOPE * xv;
                    sv[vt][ot][r] = f2bf(xv * s + b);
                }
        }
    }

    // ---- phase R: taps P133 on A2 with Wf3, bn3; y = r + s ----
    {
        const int TR[9] = {9, 10, 11, 12, 13, 14, 15, 16, 17};
        int rows[9][2];
#pragma unroll
        for (int t = 0; t < 9; ++t)
#pragma unroll
            for (int vt = 0; vt < 2; ++vt) {
                int n = n0 + vt0 + vt * 16 + m;
                rows[t][vt] = (n < N) ? nbr[(size_t)TR[t] * N + n] : -1;
            }
        __builtin_amdgcn_sched_barrier(0);

        bool act[9][2];
#pragma unroll
        for (int t = 0; t < 9; ++t)
#pragma unroll
            for (int vt = 0; vt < 2; ++vt)
                act[t][vt] = __ballot(rows[t][vt] >= 0) != 0ull;

        f32x4 acc[2][2];
#pragma unroll
        for (int vt = 0; vt < 2; ++vt)
#pragma unroll
            for (int ot = 0; ot < 2; ++ot) acc[vt][ot] = {0.f, 0.f, 0.f, 0.f};

#pragma unroll
        for (int g = 0; g < 3; ++g) {
            bf16x8 A[3][2];
#pragma unroll
            for (int i = 0; i < 3; ++i)
#pragma unroll
                for (int vt = 0; vt < 2; ++vt) {
                    const int t = g * 3 + i;
                    A[i][vt] = Z8;
                    if (act[t][vt]) {
                        int row = rows[t][vt];
                        if (row >= 0)
                            A[i][vt] = *(const bf16x8*)(A2f + (size_t)row * 32 + q * 8);
                    }
                }
            __builtin_amdgcn_sched_barrier(0);

#pragma unroll
            for (int i = 0; i < 3; ++i) {
                const int t = g * 3 + i;
                if (!(act[t][0] || act[t][1])) continue;
                const uint16_t* wb = Wf3 + t * 2048 + m * 32 + q * 8;
                bf16x8 B00 = *(const bf16x8*)(wb);
                bf16x8 B10 = *(const bf16x8*)(wb + 1024);
                bf16x8 B01 = *(const bf16x8*)(wb + 512);
                bf16x8 B11 = *(const bf16x8*)(wb + 1536);
#pragma unroll
                for (int vt = 0; vt < 2; ++vt) {
                    if (!act[t][vt]) continue;
                    acc[vt][0] = MFMA_BF16(A[i][vt], B00, acc[vt][0]);
                    acc[vt][0] = MFMA_BF16(A[i][vt], B10, acc[vt][0]);
                    acc[vt][1] = MFMA_BF16(A[i][vt], B01, acc[vt][1]);
                    acc[vt][1] = MFMA_BF16(A[i][vt], B11, acc[vt][1]);
                }
            }
        }

#pragma unroll
        for (int ot = 0; ot < 2; ++ot) {
            int ch = ot * 16 + m;
            const float* bn = bnf + 3 * 128;
            float ga = bn[ch], be = bn[32 + ch];
            float mu = bn[64 + ch], va = bn[96 + ch];
            float s = ga * rsqrtf(va + BN_EPS);
            float b = be - mu * s;
#pragma unroll
            for (int vt = 0; vt < 2; ++vt)
#pragma unroll
                for (int r = 0; r < 4; ++r) {
                    int vox = n0 + vt0 + vt * 16 + q * 4 + r;
                    if (vox >= N) continue;
                    float xv = acc[vt][ot][r];
                    xv = (xv >= 0.f) ? xv : SLOPE * xv;
                    float o = xv * s + b + bf2f(sv[vt][ot][r]);
                    y16[(size_t)vox * 32 + ch] = f2bf(o);
                }
        }
    }
}

// ---------------------------------------------------------------------------
// k_recon: 7 unique taps on y. Per-axis-group accumulators with partial
// sigmoid epilogue. Center fragment loaded once. Ballot-skip.
// ---------------------------------------------------------------------------
__launch_bounds__(256, 4)
__global__ void k_recon(const uint16_t* __restrict__ y16,
                        const uint16_t* __restrict__ xprobe,
                        const int* __restrict__ nbr,
                        const uint16_t* __restrict__ Wf4,
                        const float* __restrict__ bnf,
                        void* __restrict__ out_, int N)
{
    const int out_f32 = detect_f32_inline(xprobe);
    const int tid = threadIdx.x;
    const int n0  = blockIdx.x * 128;
    const int lane = tid & 63;
    const int m = lane & 15, q = lane >> 4;
    const int vt0 = (tid >> 6) * 32;
    const bf16x8 Z8 = {0, 0, 0, 0, 0, 0, 0, 0};

    const int ut[7] = {4, 22, 10, 16, 12, 14, 13};
    int rows[7][2];
#pragma unroll
    for (int t = 0; t < 7; ++t)
#pragma unroll
        for (int vt = 0; vt < 2; ++vt) {
            int n = n0 + vt0 + vt * 16 + m;
            rows[t][vt] = (n < N) ? nbr[(size_t)ut[t] * N + n] : -1;
        }
    __builtin_amdgcn_sched_barrier(0);

    bool act[7][2];
#pragma unroll
    for (int t = 0; t < 7; ++t)
#pragma unroll
        for (int vt = 0; vt < 2; ++vt)
            act[t][vt] = __ballot(rows[t][vt] >= 0) != 0ull;

    bf16x8 A6[2];
#pragma unroll
    for (int vt = 0; vt < 2; ++vt) {
        int row = rows[6][vt];
        A6[vt] = Z8;
        if (row >= 0)
            A6[vt] = *(const bf16x8*)(y16 + (size_t)row * 32 + q * 8);
    }

    float gsum[2][2][4];
#pragma unroll
    for (int vt = 0; vt < 2; ++vt)
#pragma unroll
        for (int ot = 0; ot < 2; ++ot)
#pragma unroll
            for (int r = 0; r < 4; ++r) gsum[vt][ot][r] = 0.f;

#pragma unroll
    for (int g = 0; g < 3; ++g) {
        f32x4 acc[2][2];
#pragma unroll
        for (int vt = 0; vt < 2; ++vt)
#pragma unroll
            for (int ot = 0; ot < 2; ++ot) acc[vt][ot] = {0.f, 0.f, 0.f, 0.f};

        bf16x8 Ae[2][2];
#pragma unroll
        for (int s2 = 0; s2 < 2; ++s2)
#pragma unroll
            for (int vt = 0; vt < 2; ++vt) {
                const int slot = 2 * g + s2;
                Ae[s2][vt] = Z8;
                if (act[slot][vt]) {
                    int row = rows[slot][vt];
                    if (row >= 0)
                        Ae[s2][vt] = *(const bf16x8*)(y16 + (size_t)row * 32 + q * 8);
                }
            }
        __builtin_amdgcn_sched_barrier(0);

#pragma unroll
        for (int s2 = 0; s2 < 2; ++s2) {
            const int slot = 2 * g + s2;
            if (!(act[slot][0] || act[slot][1])) continue;
            const int t = g * 3 + s2 * 2;
            const uint16_t* wb = Wf4 + t * 2048 + m * 32 + q * 8;
            bf16x8 B00 = *(const bf16x8*)(wb);
            bf16x8 B10 = *(const bf16x8*)(wb + 1024);
            bf16x8 B01 = *(const bf16x8*)(wb + 512);
            bf16x8 B11 = *(const bf16x8*)(wb + 1536);
#pragma unroll
            for (int vt = 0; vt < 2; ++vt) {
                if (!act[slot][vt]) continue;
                acc[vt][0] = MFMA_BF16(Ae[s2][vt], B00, acc[vt][0]);
                acc[vt][0] = MFMA_BF16(Ae[s2][vt], B10, acc[vt][0]);
                acc[vt][1] = MFMA_BF16(Ae[s2][vt], B01, acc[vt][1]);
                acc[vt][1] = MFMA_BF16(Ae[s2][vt], B11, acc[vt][1]);
            }
        }
        {
            const uint16_t* wb = Wf4 + (g * 3 + 1) * 2048 + m * 32 + q * 8;
            bf16x8 B00 = *(const bf16x8*)(wb);
            bf16x8 B10 = *(const bf16x8*)(wb + 1024);
            bf16x8 B01 = *(const bf16x8*)(wb + 512);
            bf16x8 B11 = *(const bf16x8*)(wb + 1536);
#pragma unroll
            for (int vt = 0; vt < 2; ++vt) {
                acc[vt][0] = MFMA_BF16(A6[vt], B00, acc[vt][0]);
                acc[vt][0] = MFMA_BF16(A6[vt], B10, acc[vt][0]);
                acc[vt][1] = MFMA_BF16(A6[vt], B01, acc[vt][1]);
                acc[vt][1] = MFMA_BF16(A6[vt], B11, acc[vt][1]);
            }
        }

#pragma unroll
        for (int ot = 0; ot < 2; ++ot) {
            int ch = ot * 16 + m;
            const float* p = bnf + (size_t)(4 + g) * 128;
            float scl = p[ch] * rsqrtf(p[96 + ch] + BN_EPS);
            float sh = p[32 + ch] - p[64 + ch] * scl;
#pragma unroll
            for (int vt = 0; vt < 2; ++vt)
#pragma unroll
                for (int r = 0; r < 4; ++r)
                    gsum[vt][ot][r] +=
                        1.f / (1.f + __expf(-(acc[vt][ot][r] + sh)));
        }
    }

#pragma unroll
    for (int ot = 0; ot < 2; ++ot) {
        int ch = ot * 16 + m;
#pragma unroll
        for (int vt = 0; vt < 2; ++vt)
#pragma unroll
            for (int r = 0; r < 4; ++r) {
                int vox = n0 + vt0 + vt * 16 + q * 4 + r;
                if (vox >= N) continue;
                float o = gsum[vt][ot][r] * bf2f(y16[(size_t)vox * 32 + ch]);
                if (out_f32)
                    ((float*)out_)[(size_t)vox * 32 + ch] = o;
                else
                    ((uint16_t*)out_)[(size_t)vox * 32 + ch] = f2bf(o);
            }
    }
}

// ---------------------------------------------------------------------------
// Fallback VALU tier (round-4 proven) for tiny ws.
// ---------------------------------------------------------------------------
#define WC_W1   0
#define WC_W12  4608
#define WC_W2   13824
#define WC_W3   18432
#define WC_WR1  27648
#define WC_WR2  30720
#define WC_WR3  33792
#define WC_BNP  36864
#define WC_END  37760

__global__ void canon_weights_fb(WSrcs srcs, float* __restrict__ Wc,
                                 const uint16_t* __restrict__ xprobe)
{
    int f32 = detect_f32_inline(xprobe);
    const int offs[9] = {WC_W1, WC_W12, WC_W2, WC_W3, WC_WR1, WC_WR2,
                         WC_WR3, WC_BNP, WC_END};
    int i = blockIdx.x * 256 + threadIdx.x;
    if (i >= WC_END) return;
    int t = 0;
#pragma unroll
    for (int k = 1; k < 8; ++k) if (i >= offs[k]) t = k;
    Wc[i] = readw(srcs.p[t], i - offs[t], f32);
}

__global__ void canon_x_bf(const void* __restrict__ xsrc,
                           uint16_t* __restrict__ xc, int n)
{
    int f32 = detect_f32_inline((const uint16_t*)xsrc);
    for (int i = blockIdx.x * blockDim.x + threadIdx.x; i < n;
         i += gridDim.x * blockDim.x) {
        float v = f32 ? ((const float*)xsrc)[i]
                      : bf2f(((const uint16_t*)xsrc)[i]);
        xc[i] = f2bf(v);
    }
}

template<int CIN>
__launch_bounds__(256)
__global__ void conv_bn_lrelu_bf(const uint16_t* __restrict__ feat,
                                 const int* __restrict__ nbr,
                                 const float* __restrict__ Wg,
                                 const float* __restrict__ bnp,
                                 const uint16_t* __restrict__ addsrc,
                                 uint16_t* __restrict__ out,
                                 Taps9 taps, int N)
{
    __shared__ float Wl[9 * CIN * 32];
    __shared__ float fs[CIN][128];
    __shared__ int   sidx[128];
    __shared__ float bns[32], bnb[32];

    const int tid = threadIdx.x;
    const int n0  = blockIdx.x * 128;

    for (int i = tid; i < 9 * CIN * 32; i += 256) Wl[i] = Wg[i];
    if (tid < 32) {
        float g = bnp[tid], b = bnp[32 + tid];
        float mu = bnp[64 + tid], va = bnp[96 + tid];
        float s = g * rsqrtf(va + BN_EPS);
        bns[tid] = s; bnb[tid] = b - mu * s;
    }
    float acc[4][4];
#pragma unroll
    for (int v = 0; v < 4; ++v)
#pragma unroll
        for (int j = 0; j < 4; ++j) acc[v][j] = 0.f;

    const int vb = (tid >> 3) << 2, cg2 = (tid & 7) << 2;
    const int r = tid >> 1, h = tid & 1, j0 = h * (CIN / 2);

#pragma unroll 1
    for (int t = 0; t < 9; ++t) {
        __syncthreads();
        if (tid < 128) {
            int n = n0 + tid;
            sidx[tid] = (n < N) ? nbr[(size_t)taps.t[t] * N + n] : -1;
        }
        __syncthreads();
        int mm = sidx[r];
        if (mm >= 0) {
            const uint16_t* src = feat + (size_t)mm * CIN + j0;
#pragma unroll
            for (int qq = 0; qq < CIN / 2; qq += 8) {
                uint4 u = *reinterpret_cast<const uint4*>(src + qq);
                fs[j0 + qq + 0][r] = bflo(u.x); fs[j0 + qq + 1][r] = bfhi(u.x);
                fs[j0 + qq + 2][r] = bflo(u.y); fs[j0 + qq + 3][r] = bfhi(u.y);
                fs[j0 + qq + 4][r] = bflo(u.z); fs[j0 + qq + 5][r] = bfhi(u.z);
                fs[j0 + qq + 6][r] = bflo(u.w); fs[j0 + qq + 7][r] = bfhi(u.w);
            }
        } else {
#pragma unroll
            for (int qq = 0; qq < CIN / 2; ++qq) fs[j0 + qq][r] = 0.f;
        }
        __syncthreads();
        const float* wk = Wl + t * (CIN * 32) + cg2;
#pragma unroll
        for (int ci = 0; ci < CIN; ++ci) {
            float4 f = *reinterpret_cast<const float4*>(&fs[ci][vb]);
            float4 w = *reinterpret_cast<const float4*>(wk + ci * 32);
            acc[0][0] += f.x * w.x; acc[0][1] += f.x * w.y; acc[0][2] += f.x * w.z; acc[0][3] += f.x * w.w;
            acc[1][0] += f.y * w.x; acc[1][1] += f.y * w.y; acc[1][2] += f.y * w.z; acc[1][3] += f.y * w.w;
            acc[2][0] += f.z * w.x; acc[2][1] += f.z * w.y; acc[2][2] += f.z * w.z; acc[2][3] += f.z * w.w;
            acc[3][0] += f.w * w.x; acc[3][1] += f.w * w.y; acc[3][2] += f.w * w.z; acc[3][3] += f.w * w.w;
        }
    }
#pragma unroll
    for (int v = 0; v < 4; ++v) {
        int n = n0 + vb + v;
        if (n >= N) continue;
        ushort4 st;
        uint16_t* ov = (uint16_t*)&st;
#pragma unroll
        for (int j = 0; j < 4; ++j) {
            float x = acc[v][j];
            x = (x >= 0.f) ? x : SLOPE * x;
            float o = x * bns[cg2 + j] + bnb[cg2 + j];
            if (addsrc) o += bf2f(addsrc[(size_t)n * 32 + cg2 + j]);
            ov[j] = f2bf(o);
        }
        *reinterpret_cast<ushort4*>(out + (size_t)n * 32 + cg2) = st;
    }
}

__launch_bounds__(256, 4)
__global__ void recon_gate_bf(const uint16_t* __restrict__ y,
                              const int* __restrict__ nbr,
                              const float* __restrict__ Wc,
                              const uint16_t* __restrict__ xprobe,
                              void* __restrict__ out_, int N)
{
    __shared__ float Wl[3 * 32 * 32];
    __shared__ float fs[32][128];
    __shared__ int   sidx[128];
    __shared__ float scl[3][32], shf[3][32];

    const int tid = threadIdx.x;
    const int n0  = blockIdx.x * 128;
    const int out_f32 = detect_f32_inline(xprobe);

    if (tid < 96) {
        int g = tid >> 5, c = tid & 31;
        const float* p = Wc + WC_BNP + (size_t)(4 + g) * 128;
        float ga = p[c], be = p[32 + c], mu = p[64 + c], va = p[96 + c];
        float s = ga * rsqrtf(va + BN_EPS);
        scl[g][c] = s; shf[g][c] = be - mu * s;
    }
    const int vb = (tid >> 3) << 2, cg2 = (tid & 7) << 2;
    const int r = tid >> 1, h = tid & 1, j0 = h * 16;

    float gsum[4][4];
#pragma unroll
    for (int v = 0; v < 4; ++v)
#pragma unroll
        for (int j = 0; j < 4; ++j) gsum[v][j] = 0.f;

    const int taps[3][3] = {{4, 13, 22}, {10, 13, 16}, {12, 13, 14}};

#pragma unroll 1
    for (int g = 0; g < 3; ++g) {
        __syncthreads();
        {
            const float* src = Wc + WC_WR1 + g * 3072;
            for (int i = tid; i < 3072; i += 256)
                Wl[i] = src[i] * scl[g][i & 31];
        }
        float acc[4][4];
#pragma unroll
        for (int v = 0; v < 4; ++v)
#pragma unroll
            for (int j = 0; j < 4; ++j) acc[v][j] = 0.f;

#pragma unroll 1
        for (int k = 0; k < 3; ++k) {
            __syncthreads();
            if (tid < 128) {
                int n = n0 + tid;
                sidx[tid] = (n < N) ? nbr[(size_t)taps[g][k] * N + n] : -1;
            }
            __syncthreads();
            int mm = sidx[r];
            if (mm >= 0) {
                const uint16_t* src = y + (size_t)mm * 32 + j0;
#pragma unroll
                for (int qq = 0; qq < 16; qq += 8) {
                    uint4 u = *reinterpret_cast<const uint4*>(src + qq);
                    fs[j0 + qq + 0][r] = bflo(u.x); fs[j0 + qq + 1][r] = bfhi(u.x);
                    fs[j0 + qq + 2][r] = bflo(u.y); fs[j0 + qq + 3][r] = bfhi(u.y);
                    fs[j0 + qq + 4][r] = bflo(u.z); fs[j0 + qq + 5][r] = bfhi(u.z);
                    fs[j0 + qq + 6][r] = bflo(u.w); fs[j0 + qq + 7][r] = bfhi(u.w);
                }
            } else {
#pragma unroll
                for (int qq = 0; qq < 16; ++qq) fs[j0 + qq][r] = 0.f;
            }
            __syncthreads();
            const float* wk = Wl + k * (32 * 32) + cg2;
#pragma unroll
            for (int ci = 0; ci < 32; ++ci) {
                float4 f = *reinterpret_cast<const float4*>(&fs[ci][vb]);
                float4 w = *reinterpret_cast<const float4*>(wk + ci * 32);
                acc[0][0] += f.x * w.x; acc[0][1] += f.x * w.y; acc[0][2] += f.x * w.z; acc[0][3] += f.x * w.w;
                acc[1][0] += f.y * w.x; acc[1][1] += f.y * w.y; acc[1][2] += f.y * w.z; acc[1][3] += f.y * w.w;
                acc[2][0] += f.z * w.x; acc[2][1] += f.z * w.y; acc[2][2] += f.z * w.z; acc[2][3] += f.z * w.w;
                acc[3][0] += f.w * w.x; acc[3][1] += f.w * w.y; acc[3][2] += f.w * w.z; acc[3][3] += f.w * w.w;
            }
        }
#pragma unroll
        for (int v = 0; v < 4; ++v)
#pragma unroll
            for (int j = 0; j < 4; ++j) {
                float x = acc[v][j] + shf[g][cg2 + j];
                gsum[v][j] += 1.f / (1.f + __expf(-x));
            }
    }
#pragma unroll
    for (int v = 0; v < 4; ++v) {
        int n = n0 + vb + v;
        if (n >= N) continue;
#pragma unroll
        for (int j = 0; j < 4; ++j) {
            float yv = bf2f(y[(size_t)n * 32 + cg2 + j]);
            float o = gsum[v][j] * yv;
            if (out_f32) ((float*)out_)[(size_t)n * 32 + cg2 + j] = o;
            else ((uint16_t*)out_)[(size_t)n * 32 + cg2 + j] = f2bf(o);
        }
    }
}

// ---------------------------------------------------------------------------
extern "C" void kernel_launch(void* const* d_in, const int* in_sizes, int n_in,
                              void* d_out, int out_size, void* d_ws, size_t ws_size,
                              hipStream_t stream)
{
    (void)n_in; (void)out_size;
    const void* x   = d_in[0];
    const int*  nbr = (const int*)d_in[1];
    const int N = in_sizes[0] / 16;
    const uint16_t* xprobe = (const uint16_t*)x;

    dim3 block(256);
    const int gx = (N + 127) / 128;
    Taps9 p133 = {{9, 10, 11, 12, 13, 14, 15, 16, 17}};
    Taps9 p313 = {{3, 4, 5, 12, 13, 14, 21, 22, 23}};
    WSrcs ws8 = {{ d_in[2], d_in[3], d_in[4], d_in[5],
                   d_in[6], d_in[7], d_in[8], d_in[9] }};

    // ws layout (MFMA tier): bnf [0,4096) | Wf [4096,+184320) | xi | A1 | A2 | Y
    float*    bnf = (float*)d_ws;
    uint16_t* Wf  = (uint16_t*)((char*)d_ws + 4096);
    const size_t base2 = 4096u + (size_t)WF_END * 2;   // 188416
    uint16_t* xi  = (uint16_t*)((char*)d_ws + base2);  // [N][32] interleaved
    uint16_t* A1  = xi + (size_t)N * 32;               // [N][32] bf16-hi
    uint16_t* A2  = A1 + (size_t)N * 32;
    uint16_t* Y   = A2 + (size_t)N * 32;
    const size_t need = base2 + 4u * (size_t)N * 64;

    if (ws_size >= need) {
        prep_combo<<<PREP_BLOCKS + 1024, block, 0, stream>>>(
            x, ws8, Wf, bnf, (uint32_t*)xi, N * 16);
        // stage 1: s1 -> A1, r1 -> A2 (one gy=2 launch, R10-proven kernel)
        ConvJob c1 = {xi, Wf + 0 * WFS, bnf + 0 * 128, nullptr, A1, p133};
        ConvJob c2 = {xi, Wf + 2 * WFS, bnf + 2 * 128, nullptr, A2, p313};
        conv_mfma6<<<dim3(gx, 2), block, 0, stream>>>(c1, c2, nbr, N);
        // stage 2 fused: y = f2bf(conv(A2,W3)+bn3 lrelu  +  bf16(conv(A1,W12)))
        k_dual2<<<gx, block, 0, stream>>>(A1, A2, Wf + 1 * WFS, Wf + 3 * WFS,
                                          bnf, nbr, Y, N);
        k_recon<<<gx, block, 0, stream>>>(Y, xprobe, nbr, Wf + 4 * WFS, bnf,
                                          d_out, N);
    } else {
        // VALU fallback (all-bf16)
        float*    Wc = (float*)d_ws;
        uint16_t* xc = (uint16_t*)((char*)d_ws + (size_t)WC_END * 4 + 256);
        uint16_t* A  = (uint16_t*)d_out;
        uint16_t* B  = xc + (size_t)N * 16;
        const float* bn0 = Wc + WC_BNP + 0 * 128;
        const float* bn1 = Wc + WC_BNP + 1 * 128;
        const float* bn2 = Wc + WC_BNP + 2 * 128;
        const float* bn3 = Wc + WC_BNP + 3 * 128;
        canon_weights_fb<<<(WC_END + 255) / 256, block, 0, stream>>>(ws8, Wc, xprobe);
        canon_x_bf<<<1024, block, 0, stream>>>(x, xc, N * 16);
        conv_bn_lrelu_bf<16><<<gx, block, 0, stream>>>(xc, nbr, Wc + WC_W1,  bn0, nullptr, A, p133, N);
        conv_bn_lrelu_bf<32><<<gx, block, 0, stream>>>(A,  nbr, Wc + WC_W12, bn1, nullptr, B, p313, N);
        conv_bn_lrelu_bf<16><<<gx, block, 0, stream>>>(xc, nbr, Wc + WC_W2,  bn2, nullptr, A, p313, N);
        conv_bn_lrelu_bf<32><<<gx, block, 0, stream>>>(A,  nbr, Wc + WC_W3,  bn3, B,       B, p133, N);
        recon_gate_bf<<<gx, block, 0, stream>>>(B, nbr, Wc, xprobe, d_out, N);
    }
}